// Round 4
// baseline (28810.117 us; speedup 1.0000x reference)
//
#include <hip/hip_runtime.h>
#include <cstdint>
#include <cstddef>

// ============================================================================
// Persistent fused 2-layer LSTM + FC for MI355X (gfx950) — Round 4.
// R3 post-mortem: VGPR_Count=128 < 144-float live weight set => scratch spill
// in the hot loop (WRITE_SIZE 5.5 GB of scratch churn) + serial per-batch
// shuffle-reduction chains + 4-hop sweeper barrier. R4:
//   - Staging via 2-stage pipeline (4-8 u64 in flight), no giant temp arrays
//     -> weights stay VGPR-resident (expect VGPR_Count ~170-220, no spill).
//   - Gate reductions batched 4-wide: 4 independent butterfly chains pipeline
//     instead of serializing (~700cy chain latency amortized 4x).
//   - Flat barrier: every block polls all 256 flags (2 LLC hops, no sweeper).
// Structure otherwise as R3: 128 L0-blocks || 128 L1-blocks layer pipeline,
// h in [t][j][b] (contiguous 128B/wave stores), LDS transpose stride 33/17.
// ============================================================================

#define NBLK 256
#define NTHR 512

namespace {
constexpr int kB = 32, kT = 512, kI = 256, kH = 1024, kO = 512, kTR = 500;
constexpr int kRounds = 502;                 // r = 0..501
constexpr size_t kBarFloats = 2048;          // flags[256]
constexpr size_t kH1Off = kBarFloats;        // h1_state[502][1024][32]
constexpr size_t kH1Len = (size_t)kRounds * kH * kB;
constexpr size_t kH2Off = kH1Off + kH1Len;   // h2_state[2][1024][32]
constexpr int kXchg = 34816;                 // gate-exchange region (1024 f)
constexpr int kLdsFloats = kXchg + 1024;
constexpr int kLdsBytes = kLdsFloats * 4;    // 143360 B -> 1 block/CU
}

typedef unsigned long long u64;

// ---------------------------------------------------------------------------
// Flat grid barrier (monotonic steps 1..501): each block release-stores its
// flag, then one wave polls ALL 256 flags (4/lane). Two LLC hops total.
// ---------------------------------------------------------------------------
__device__ __forceinline__ void grid_barrier(unsigned* flags, unsigned step) {
  __syncthreads();                      // drains vmcnt: h stores complete
  const int tid = threadIdx.x;
  if (tid < 64) {
    if (tid == 0)
      __hip_atomic_store(&flags[blockIdx.x], step, __ATOMIC_RELEASE,
                         __HIP_MEMORY_SCOPE_AGENT);
    const int l4 = tid << 2;
    bool done;
    do {
      unsigned ok = 1u;
#pragma unroll
      for (int k = 0; k < 4; ++k)
        ok &= (unsigned)(__hip_atomic_load(&flags[l4 + k], __ATOMIC_RELAXED,
                                           __HIP_MEMORY_SCOPE_AGENT) >= step);
      done = __all((int)ok);
      if (!done) __builtin_amdgcn_s_sleep(1);
    } while (!done);
  }
  if (tid == 0)
    (void)__hip_atomic_load(&flags[0], __ATOMIC_ACQUIRE,
                            __HIP_MEMORY_SCOPE_AGENT);
  __syncthreads();
}

// Merged 4-value butterfly: lane ends with total of a_{lane&3}.
__device__ __forceinline__ float merged_gate_reduce(float a0, float a1,
                                                    float a2, float a3,
                                                    int lane) {
  a0 += __shfl_xor(a0, 1); a1 += __shfl_xor(a1, 1);
  a2 += __shfl_xor(a2, 1); a3 += __shfl_xor(a3, 1);
  float v0 = (lane & 1) ? a1 : a0;
  float v1 = (lane & 1) ? a3 : a2;
  v0 += __shfl_xor(v0, 2); v1 += __shfl_xor(v1, 2);
  float u = (lane & 2) ? v1 : v0;
  u += __shfl_xor(u, 4);
  u += __shfl_xor(u, 8);
  u += __shfl_xor(u, 16);
  u += __shfl_xor(u, 32);
  return u;
}

__device__ __forceinline__ float wave_sum(float x) {
  x += __shfl_xor(x, 1);  x += __shfl_xor(x, 2);
  x += __shfl_xor(x, 4);  x += __shfl_xor(x, 8);
  x += __shfl_xor(x, 16); x += __shfl_xor(x, 32);
  return x;
}

__device__ __forceinline__ float sigmoid_f(float x) {
  return __builtin_amdgcn_rcpf(1.f + __expf(-x));
}
__device__ __forceinline__ float tanh_f(float x) {
  return 1.f - 2.f * __builtin_amdgcn_rcpf(1.f + __expf(2.f * x));
}

__device__ __forceinline__ u64 ld_agent_u64(const float* p) {
  return __hip_atomic_load((const u64*)p, __ATOMIC_RELAXED,
                           __HIP_MEMORY_SCOPE_AGENT);
}
__device__ __forceinline__ void st_agent_f32(float* p, float v) {
  __hip_atomic_store(p, v, __ATOMIC_RELAXED, __HIP_MEMORY_SCOPE_AGENT);
}
__device__ __forceinline__ float u64_lo(u64 v) {
  return __uint_as_float((unsigned)(v & 0xffffffffull));
}
__device__ __forceinline__ float u64_hi(u64 v) {
  return __uint_as_float((unsigned)(v >> 32));
}

__global__ void __launch_bounds__(256, 1) lstm_init_kernel(float* ws) {
  const size_t idx = (size_t)blockIdx.x * blockDim.x + threadIdx.x;
  if (idx < kBarFloats) ((unsigned*)ws)[idx] = 0u;
  if (idx < (size_t)kB * kH) {
    ws[kH1Off + idx] = 0.f;             // h1_state[0] = 0
    ws[kH2Off + idx] = 0.f;             // h2_state slot 0 = 0
  }
}

__global__ void __launch_bounds__(NTHR, 2) lstm_persist_kernel(
    const float* __restrict__ x,
    const float* __restrict__ Wih0, const float* __restrict__ Whh0,
    const float* __restrict__ bih0, const float* __restrict__ bhh0,
    const float* __restrict__ Wih1, const float* __restrict__ Whh1,
    const float* __restrict__ bih1, const float* __restrict__ bhh1,
    const float* __restrict__ Wfc, const float* __restrict__ bfc,
    float* __restrict__ out, float* __restrict__ ws) {
  const int tid = threadIdx.x;
  const int bk = blockIdx.x;
  const int w = tid >> 6;               // wave 0..7
  const int lane = tid & 63;
  unsigned* flags = (unsigned*)ws;
  float* h1s = ws + kH1Off;             // [502][1024][32]
  float* h2s = ws + kH2Off;             // [2][1024][32]
  extern __shared__ float lds[];

  if (bk < 128) {
    // ========================= Layer 0 =========================
    const int j0 = bk * 8 + w;          // owned hidden unit
    float whh[4][16], wih[4][4], bias[4];
#pragma unroll
    for (int g = 0; g < 4; ++g) {
#pragma unroll
      for (int c = 0; c < 16; ++c)
        whh[g][c] = Whh0[(size_t)(g * kH + j0) * kH + c * 64 + lane];
#pragma unroll
      for (int c = 0; c < 4; ++c)
        wih[g][c] = Wih0[(size_t)(g * kH + j0) * kI + c * 64 + lane];
      bias[g] = bih0[g * kH + j0] + bhh0[g * kH + j0];
    }
    float creg = 0.f;                   // c for (b=lane, j0), lanes 0..31

    for (int r = 0; r <= 500; ++r) {
      // ---- stage h1_state[r] ([j][b]) -> lds [k][b] stride 33, pipelined
      {
        const float* src = h1s + (size_t)r * (kH * kB);
        u64 c0 = ld_agent_u64(src + (size_t)(0 * NTHR + tid) * 2);
        u64 c1 = ld_agent_u64(src + (size_t)(1 * NTHR + tid) * 2);
        u64 c2 = ld_agent_u64(src + (size_t)(2 * NTHR + tid) * 2);
        u64 c3 = ld_agent_u64(src + (size_t)(3 * NTHR + tid) * 2);
        __syncthreads();                // prior-round LDS reads complete
#pragma unroll
        for (int i = 0; i < 32; i += 4) {
          u64 n0 = 0, n1 = 0, n2 = 0, n3 = 0;
          if (i + 4 < 32) {
            n0 = ld_agent_u64(src + (size_t)((i + 4) * NTHR + tid) * 2);
            n1 = ld_agent_u64(src + (size_t)((i + 5) * NTHR + tid) * 2);
            n2 = ld_agent_u64(src + (size_t)((i + 6) * NTHR + tid) * 2);
            n3 = ld_agent_u64(src + (size_t)((i + 7) * NTHR + tid) * 2);
          }
#pragma unroll
          for (int k = 0; k < 4; ++k) {
            const u64 v = (k == 0) ? c0 : (k == 1) ? c1 : (k == 2) ? c2 : c3;
            const int idx = (i + k) * NTHR + tid;
            const int j = idx >> 4, q = (idx & 15) * 2;
            lds[j * 33 + q]     = u64_lo(v);
            lds[j * 33 + q + 1] = u64_hi(v);
          }
          c0 = n0; c1 = n1; c2 = n2; c3 = n3;
        }
      }
      __syncthreads();

      // ---- gates, 4 batches per group (4 independent reduce chains)
      for (int bt = 0; bt < 32; bt += 4) {
        float xv[4][4];
#pragma unroll
        for (int bi = 0; bi < 4; ++bi) {
          const float* xp = x + ((size_t)(bt + bi) * kT + r) * kI + lane;
          xv[bi][0] = xp[0];   xv[bi][1] = xp[64];
          xv[bi][2] = xp[128]; xv[bi][3] = xp[192];
        }
        float acc[4][4];
#pragma unroll
        for (int bi = 0; bi < 4; ++bi) {
          float a0 = 0.f, a1 = 0.f, a2 = 0.f, a3 = 0.f;
#pragma unroll
          for (int c = 0; c < 16; ++c) {
            const float hv = lds[(c * 64 + lane) * 33 + bt + bi];
            a0 = fmaf(hv, whh[0][c], a0);
            a1 = fmaf(hv, whh[1][c], a1);
            a2 = fmaf(hv, whh[2][c], a2);
            a3 = fmaf(hv, whh[3][c], a3);
          }
#pragma unroll
          for (int c = 0; c < 4; ++c) {
            a0 = fmaf(xv[bi][c], wih[0][c], a0);
            a1 = fmaf(xv[bi][c], wih[1][c], a1);
            a2 = fmaf(xv[bi][c], wih[2][c], a2);
            a3 = fmaf(xv[bi][c], wih[3][c], a3);
          }
          acc[bi][0] = a0; acc[bi][1] = a1; acc[bi][2] = a2; acc[bi][3] = a3;
        }
        const float u0 = merged_gate_reduce(acc[0][0], acc[0][1], acc[0][2],
                                            acc[0][3], lane);
        const float u1 = merged_gate_reduce(acc[1][0], acc[1][1], acc[1][2],
                                            acc[1][3], lane);
        const float u2 = merged_gate_reduce(acc[2][0], acc[2][1], acc[2][2],
                                            acc[2][3], lane);
        const float u3 = merged_gate_reduce(acc[3][0], acc[3][1], acc[3][2],
                                            acc[3][3], lane);
        const float sel = (lane & 8) ? ((lane & 4) ? u3 : u2)
                                     : ((lane & 4) ? u1 : u0);
        if (lane < 16) lds[kXchg + w * 128 + bt * 4 + lane] = sel;
      }
      if (lane < kB) {                  // gate math for batch b=lane
        const float4 g4 = *(const float4*)&lds[kXchg + w * 128 + lane * 4];
        const float gi = sigmoid_f(g4.x + bias[0]);
        const float gf = sigmoid_f(g4.y + bias[1]);
        const float gg = tanh_f(g4.z + bias[2]);
        const float go = sigmoid_f(g4.w + bias[3]);
        creg = gf * creg + gi * gg;
        const float hnew = go * tanh_f(creg);
        st_agent_f32(&h1s[(size_t)(r + 1) * (kH * kB) + j0 * kB + lane],
                     hnew);
      }
      grid_barrier(flags, (unsigned)(r + 1));
    }
  } else {
    // ==================== Layer 1 + fused FC ====================
    const int bl = bk - 128;
    const int j1 = bl * 8 + w;
    float wih[4][16], whh[4][16], bias[4], wfc[16];
#pragma unroll
    for (int g = 0; g < 4; ++g) {
#pragma unroll
      for (int c = 0; c < 16; ++c) {
        wih[g][c] = Wih1[(size_t)(g * kH + j1) * kH + c * 64 + lane];
        whh[g][c] = Whh1[(size_t)(g * kH + j1) * kH + c * 64 + lane];
      }
      bias[g] = bih1[g * kH + j1] + bhh1[g * kH + j1];
    }
    const bool fcw = (w < 4);           // waves 0-3 own FC col bl*4+w
    float bfco = 0.f;
#pragma unroll
    for (int c = 0; c < 16; ++c)
      wfc[c] = fcw ? Wfc[(size_t)(bl * 4 + w) * kH + c * 64 + lane] : 0.f;
    if (fcw) bfco = bfc[bl * 4 + w];
    float creg0 = 0.f, creg1 = 0.f;     // c for b=lane(half0), b=16+lane
    float* ldsH1 = lds;                 // [k][b-half], stride 17
    float* ldsH2 = lds + 17408;

    grid_barrier(flags, 1u);            // round 0: no L1 work
    for (int r = 1; r <= 501; ++r) {
      const float* s1 = h1s + (size_t)r * (kH * kB);
      const float* s2 = h2s + (size_t)((r - 1) & 1) * (kH * kB);
#pragma unroll
      for (int half = 0; half < 2; ++half) {
        // ---- stage h1[r] & h2[r-1] halves, pipelined (8 u64 in flight)
        {
          const float* p1 = s1 + half * 16;
          const float* p2 = s2 + half * 16;
          // element mapping: idx=i*NTHR+tid in [0,8192): j=idx>>3, q=(idx&7)*2
          u64 a0, a1, b0, b1;
          {
            const int i0 = 0 * NTHR + tid, i1 = 1 * NTHR + tid;
            a0 = ld_agent_u64(p1 + (i0 >> 3) * kB + (i0 & 7) * 2);
            a1 = ld_agent_u64(p1 + (i1 >> 3) * kB + (i1 & 7) * 2);
            b0 = ld_agent_u64(p2 + (i0 >> 3) * kB + (i0 & 7) * 2);
            b1 = ld_agent_u64(p2 + (i1 >> 3) * kB + (i1 & 7) * 2);
          }
          __syncthreads();              // previous compute's LDS reads done
#pragma unroll
          for (int i = 0; i < 16; i += 2) {
            u64 na0 = 0, na1 = 0, nb0 = 0, nb1 = 0;
            if (i + 2 < 16) {
              const int i0 = (i + 2) * NTHR + tid, i1 = (i + 3) * NTHR + tid;
              na0 = ld_agent_u64(p1 + (i0 >> 3) * kB + (i0 & 7) * 2);
              na1 = ld_agent_u64(p1 + (i1 >> 3) * kB + (i1 & 7) * 2);
              nb0 = ld_agent_u64(p2 + (i0 >> 3) * kB + (i0 & 7) * 2);
              nb1 = ld_agent_u64(p2 + (i1 >> 3) * kB + (i1 & 7) * 2);
            }
#pragma unroll
            for (int k = 0; k < 2; ++k) {
              const u64 va = k ? a1 : a0;
              const u64 vb = k ? b1 : b0;
              const int idx = (i + k) * NTHR + tid;
              const int j = idx >> 3, q = (idx & 7) * 2;
              ldsH1[j * 17 + q]     = u64_lo(va);
              ldsH1[j * 17 + q + 1] = u64_hi(va);
              ldsH2[j * 17 + q]     = u64_lo(vb);
              ldsH2[j * 17 + q + 1] = u64_hi(vb);
            }
            a0 = na0; a1 = na1; b0 = nb0; b1 = nb1;
          }
        }
        __syncthreads();

        float myfc = 0.f;
        for (int bt = 0; bt < 16; bt += 4) {
          float acc[4][4], fcc[4];
#pragma unroll
          for (int bi = 0; bi < 4; ++bi) {
            const int b2 = bt + bi;
            float a0 = 0.f, a1 = 0.f, a2 = 0.f, a3 = 0.f, a4 = 0.f;
#pragma unroll
            for (int c = 0; c < 16; ++c) {        // input part: h1[r]
              const float hv = ldsH1[(c * 64 + lane) * 17 + b2];
              a0 = fmaf(hv, wih[0][c], a0);
              a1 = fmaf(hv, wih[1][c], a1);
              a2 = fmaf(hv, wih[2][c], a2);
              a3 = fmaf(hv, wih[3][c], a3);
            }
#pragma unroll
            for (int c = 0; c < 16; ++c) {        // recurrent: h2[r-1]
              const float gv = ldsH2[(c * 64 + lane) * 17 + b2];
              a0 = fmaf(gv, whh[0][c], a0);
              a1 = fmaf(gv, whh[1][c], a1);
              a2 = fmaf(gv, whh[2][c], a2);
              a3 = fmaf(gv, whh[3][c], a3);
              a4 = fmaf(gv, wfc[c], a4);          // fused FC (wfc=0 if !fcw)
            }
            acc[bi][0] = a0; acc[bi][1] = a1;
            acc[bi][2] = a2; acc[bi][3] = a3;
            fcc[bi] = a4;
          }
          const float u0 = merged_gate_reduce(acc[0][0], acc[0][1],
                                              acc[0][2], acc[0][3], lane);
          const float u1 = merged_gate_reduce(acc[1][0], acc[1][1],
                                              acc[1][2], acc[1][3], lane);
          const float u2 = merged_gate_reduce(acc[2][0], acc[2][1],
                                              acc[2][2], acc[2][3], lane);
          const float u3 = merged_gate_reduce(acc[3][0], acc[3][1],
                                              acc[3][2], acc[3][3], lane);
          const float sel = (lane & 8) ? ((lane & 4) ? u3 : u2)
                                       : ((lane & 4) ? u1 : u0);
          if (lane < 16) lds[kXchg + w * 64 + bt * 4 + lane] = sel;
          if (fcw) {
            const float f0 = wave_sum(fcc[0]);
            const float f1 = wave_sum(fcc[1]);
            const float f2 = wave_sum(fcc[2]);
            const float f3 = wave_sum(fcc[3]);
            const int d = lane - bt;
            if (d >= 0 && d < 4)
              myfc = (d == 0) ? f0 : (d == 1) ? f1 : (d == 2) ? f2 : f3;
          }
        }
        if (lane < 16) {                // gate math for b = half*16+lane
          const float4 g4 = *(const float4*)&lds[kXchg + w * 64 + lane * 4];
          const float gi = sigmoid_f(g4.x + bias[0]);
          const float gf = sigmoid_f(g4.y + bias[1]);
          const float gg = tanh_f(g4.z + bias[2]);
          const float go = sigmoid_f(g4.w + bias[3]);
          float cr = half ? creg1 : creg0;
          cr = gf * cr + gi * gg;
          if (half) creg1 = cr; else creg0 = cr;
          const float hnew = go * tanh_f(cr);
          st_agent_f32(&h2s[(size_t)(r & 1) * (kH * kB) + j1 * kB +
                            half * 16 + lane], hnew);
        }
        if (fcw && r >= 2 && lane < 16) {
          const int b = half * 16 + lane;
          out[((size_t)b * kTR + (r - 2)) * kO + bl * 4 + w] = myfc + bfco;
        }
      }
      if (r <= 500) grid_barrier(flags, (unsigned)(r + 1));
    }
  }
}

extern "C" void kernel_launch(void* const* d_in, const int* in_sizes, int n_in,
                              void* d_out, int out_size, void* d_ws,
                              size_t ws_size, hipStream_t stream) {
  const float* x    = (const float*)d_in[0];
  const float* Wih0 = (const float*)d_in[1];
  const float* Whh0 = (const float*)d_in[2];
  const float* bih0 = (const float*)d_in[3];
  const float* bhh0 = (const float*)d_in[4];
  const float* Wih1 = (const float*)d_in[5];
  const float* Whh1 = (const float*)d_in[6];
  const float* bih1 = (const float*)d_in[7];
  const float* bhh1 = (const float*)d_in[8];
  const float* Wfc  = (const float*)d_in[9];
  const float* bfc  = (const float*)d_in[10];
  float* out = (float*)d_out;
  float* ws  = (float*)d_ws;

  (void)hipFuncSetAttribute((const void*)lstm_persist_kernel,
                            hipFuncAttributeMaxDynamicSharedMemorySize,
                            kLdsBytes);

  hipLaunchKernelGGL(lstm_init_kernel, dim3(128), dim3(256), 0, stream, ws);
  hipLaunchKernelGGL(lstm_persist_kernel, dim3(NBLK), dim3(NTHR), kLdsBytes,
                     stream, x, Wih0, Whh0, bih0, bhh0, Wih1, Whh1, bih1,
                     bhh1, Wfc, bfc, out, ws);
}